// Round 16
// baseline (169.348 us; speedup 1.0000x reference)
//
#include <hip/hip_runtime.h>
#include <hip/hip_fp16.h>
#include <math.h>

#define S 2048
#define D4 1024
#define NB 4
#define HS 1026          // half-spectrum column stride (1025 used)
#define TWOPI 6.283185307179586f

typedef __attribute__((ext_vector_type(8))) short bf16x8;
typedef __attribute__((ext_vector_type(4))) float f32x4;

__device__ __forceinline__ float2 cmul(float2 a, float2 b){
  return make_float2(a.x*b.x - a.y*b.y, a.x*b.y + a.y*b.x);
}
__device__ __forceinline__ float2 cadd(float2 a, float2 b){ return make_float2(a.x+b.x, a.y+b.y); }
__device__ __forceinline__ float2 csub(float2 a, float2 b){ return make_float2(a.x-b.x, a.y-b.y); }

__device__ __forceinline__ unsigned short f2bf(float f){
  unsigned int u = __builtin_bit_cast(unsigned int, f);
  unsigned int r = (u + 0x7FFFu + ((u >> 16) & 1u)) >> 16;
  return (unsigned short)r;
}
__device__ __forceinline__ float bf2f(unsigned short u){
  unsigned int x = (unsigned int)u << 16;
  return __builtin_bit_cast(float, x);
}

__device__ __forceinline__ void gld16(const unsigned short* g, unsigned short* l){
  __builtin_amdgcn_global_load_lds((const __attribute__((address_space(1))) unsigned int*)g,
                                   (__attribute__((address_space(3))) unsigned int*)l,
                                   16, 0, 0);
}

// padded twiddle fetch: table holds W^m for m=0..1023 at index m+(m>>5); W^{m+1024} = -W^m
__device__ __forceinline__ float2 twf(const float* twr, const float* twi, int m){
  int mm = m & 1023;
  float s = (m & 1024) ? -1.f : 1.f;
  int p = mm + (mm >> 5);
  return make_float2(s * twr[p], s * twi[p]);
}

// forward DFT8 (natural-order out): X[k] = sum a[n] W8^{-nk}
__device__ __forceinline__ void dft8_fwd(const float2 a[8], float2 o[8]){
  const float RH = 0.70710678118654752f;
  float2 b0 = cadd(a[0],a[4]), b1 = cadd(a[1],a[5]), b2 = cadd(a[2],a[6]), b3 = cadd(a[3],a[7]);
  float2 c0 = csub(a[0],a[4]);
  float2 t1 = csub(a[1],a[5]);
  float2 c1 = make_float2(RH*(t1.x + t1.y), RH*(t1.y - t1.x));   // * (1-i)/sqrt2
  float2 t2 = csub(a[2],a[6]);
  float2 c2 = make_float2(t2.y, -t2.x);                          // * -i
  float2 t3 = csub(a[3],a[7]);
  float2 c3 = make_float2(RH*(t3.y - t3.x), RH*(-(t3.x + t3.y)));// * (-1-i)/sqrt2
  float2 e0 = cadd(b0,b2), e1 = cadd(b1,b3);
  float2 f0 = csub(b0,b2);
  float2 f1t = csub(b1,b3); float2 f1 = make_float2(f1t.y, -f1t.x);
  o[0] = cadd(e0,e1); o[4] = csub(e0,e1);
  o[2] = cadd(f0,f1); o[6] = csub(f0,f1);
  float2 g0 = cadd(c0,c2), g1 = cadd(c1,c3);
  float2 h0 = csub(c0,c2);
  float2 h1t = csub(c1,c3); float2 h1 = make_float2(h1t.y, -h1t.x);
  o[1] = cadd(g0,g1); o[5] = csub(g0,g1);
  o[3] = cadd(h0,h1); o[7] = csub(h0,h1);
}

__device__ __forceinline__ void dft4_fwd(const float2 a[4], float2 o[4]){
  float2 b0 = cadd(a[0],a[2]), b1 = cadd(a[1],a[3]);
  float2 c0 = csub(a[0],a[2]);
  float2 c1t = csub(a[1],a[3]); float2 c1 = make_float2(c1t.y, -c1t.x);  // * -i
  o[0]=cadd(b0,b1); o[2]=csub(b0,b1); o[1]=cadd(c0,c1); o[3]=csub(c0,c1);
}
__device__ __forceinline__ void dft4_inv(const float2 a[4], float2 o[4]){
  float2 b0 = cadd(a[0],a[2]), b1 = cadd(a[1],a[3]);
  float2 c0 = csub(a[0],a[2]);
  float2 c1t = csub(a[1],a[3]); float2 c1 = make_float2(-c1t.y, c1t.x); // * +i
  o[0]=cadd(b0,b1); o[2]=csub(b0,b1); o[1]=cadd(c0,c1); o[3]=csub(c0,c1);
}

// ---------------------------------------------------------------- prep
__global__ __launch_bounds__(256) void prep_kernel(float* __restrict__ scale,
                                                   float2* __restrict__ gfilt,
                                                   float2* __restrict__ twg,
                                                   float alpha, float beta){
  int i = blockIdx.x * 256 + threadIdx.x;  // 0..2047
  float lam = (float)i / (float)S;
  float w = sinf(alpha * lam) * cosf(-2.0f * lam + beta * lam * lam);
  scale[i] = 0.95f * (1.0f + 0.1f * w);
  if (i <= 1024){
    int im = (2048 - i) & 2047;
    float th1 = 1.5f * atanf(logf((float)i  + 1e-10f));
    float th2 = 1.5f * atanf(logf((float)im + 1e-10f));
    float s1, c1, s2, c2;
    sincosf(3.0f * th1, &s1, &c1);
    sincosf(3.0f * th2, &s2, &c2);
    gfilt[i] = make_float2((c1 + c2) * 0.5f, (s1 - s2) * 0.5f);
  }
  if (i < 1024){
    float s2, c2; sincosf((float)i * (TWOPI / 2048.f), &s2, &c2);
    twg[i]        = make_float2(c2, -s2);
    twg[1024 + i] = make_float2(c2,  s2);
  }
}

// ---------------------------------------------------------------- fused converts
__global__ __launch_bounds__(256) void convert_all(const float* __restrict__ q,
                                                   const float* __restrict__ mem,
                                                   const float* __restrict__ Wq,
                                                   const float* __restrict__ Wk,
                                                   const float* __restrict__ Wv,
                                                   unsigned short* __restrict__ XqB,
                                                   unsigned short* __restrict__ XmB,
                                                   unsigned short* __restrict__ Wall,
                                                   const float* __restrict__ scale,
                                                   float cmem){
  int bid = blockIdx.x;
  if (bid < 8192){
    size_t i = ((size_t)bid * 256 + threadIdx.x) * 4;
    int s = (int)((i / D4) % S);
    float scl = scale[s];
    float4 v = *(const float4*)&q[i];
    ushort4 o;
    o.x = f2bf(v.x * scl); o.y = f2bf(v.y * scl);
    o.z = f2bf(v.z * scl); o.w = f2bf(v.w * scl);
    *(ushort4*)&XqB[i] = o;
  } else if (bid < 16384){
    size_t i = ((size_t)(bid - 8192) * 256 + threadIdx.x) * 4;
    float4 v = *(const float4*)&mem[i];
    ushort4 o;
    o.x = f2bf(v.x * cmem); o.y = f2bf(v.y * cmem);
    o.z = f2bf(v.z * cmem); o.w = f2bf(v.w * cmem);
    *(ushort4*)&XmB[i] = o;
  } else {
    int r = bid - 16384;                    // 0..3071
    int tensor = r >> 10;
    const float* Wsrc = (tensor == 0) ? Wq : (tensor == 1 ? Wk : Wv);
    size_t i = ((size_t)(r & 1023) * 256 + threadIdx.x) * 4;
    float4 v = *(const float4*)&Wsrc[i];
    ushort4 o;
    o.x = f2bf(v.x); o.y = f2bf(v.y);
    o.z = f2bf(v.z); o.w = f2bf(v.w);
    *(ushort4*)&(Wall + (size_t)tensor * D4 * D4)[i] = o;
  }
}

// ---------------------------------------------------------------- MFMA GEMM (triple-buffered, counted vmcnt)
// 128(M) x 256(N) tile, BK=64, 512 threads / 8 waves (2M x 4N), per-wave 64x64
// fragment code identical to the proven R13 kernel. THREE LDS buffers (144 KB,
// 1 block/CU, 2 waves/SIMD): iteration kt computes buf[kt%3] while staging tile
// kt+2 into buf[(kt+2)%3] — the WAR target was last read 2 iterations ago, so
// the single per-iteration s_barrier covers it with NO lgkm drain. Sync per
// K-tile = s_waitcnt vmcnt(6) (tile kt+1 resident; kt+2's 6 loads in flight,
// never drained to 0 until the tail) + one s_barrier. XOR swizzle unchanged.
#define TM 128
#define TN 256
#define TKK 64
__global__ __launch_bounds__(512) void mfma_gemm_all(const unsigned short* __restrict__ Wall,
                                                     const unsigned short* __restrict__ XqB,
                                                     const unsigned short* __restrict__ XmB,
                                                     const float* __restrict__ bq,
                                                     const float* __restrict__ bk,
                                                     const float* __restrict__ bv,
                                                     unsigned short* __restrict__ Xb){
  __shared__ unsigned short sA[3 * TM * TKK];   // 3 x 16 KB
  __shared__ unsigned short sB[3 * TN * TKK];   // 3 x 32 KB
  const int z = blockIdx.z;
  const int tensor = z >> 2, b = z & 3;
  const size_t TEN = (size_t)NB * D4 * S;
  const unsigned short* A = Wall + (size_t)tensor * D4 * D4;
  const unsigned short* B = (tensor == 0 ? XqB : XmB) + (size_t)b * S * D4;
  const float* bias = (tensor == 0) ? bq : (tensor == 1 ? bk : bv);
  unsigned short* dst = Xb + (size_t)tensor * TEN + (size_t)b * D4 * S;
  const int m0 = blockIdx.y * TM;           // gridDim.y = 8
  const int n0 = blockIdx.x * TN;           // gridDim.x = 8
  const int t = threadIdx.x;                // 0..511
  const int w = t >> 6, l = t & 63;
  const int wm = w >> 2, wn = w & 3;        // wave grid 2M x 4N -> 64x64 tile
  const int tr = t >> 3;                    // 0..63: staging row within 64-row round
  const int sc = ((t & 7) ^ (tr & 7)) * 8;  // inverse-swizzled global chunk
  const int ldst = tr * TKK + (t & 7) * 8;  // linear LDS dest within round base
  const int l15 = l & 15, lh = l >> 4;
  const int co0 = ((lh     ^ (l15 & 7)) * 8);
  const int co1 = (((4+lh) ^ (l15 & 7)) * 8);

  f32x4 acc[4][4] = {};

  // stage tile (k0) into buffer bi: A = 2 rounds of 64 rows, B = 4 rounds
#define STAGE(bi, k0) do { \
    _Pragma("unroll") \
    for (int r_ = 0; r_ < 2; ++r_) \
      gld16(A + (size_t)(m0 + r_ * 64 + tr) * D4 + (k0) + sc, \
            &sA[(bi) * (TM * TKK) + r_ * 64 * TKK + ldst]); \
    _Pragma("unroll") \
    for (int r_ = 0; r_ < 4; ++r_) \
      gld16(B + (size_t)(n0 + r_ * 64 + tr) * D4 + (k0) + sc, \
            &sB[(bi) * (TN * TKK) + r_ * 64 * TKK + ldst]); \
  } while(0)

#define COMPUTE(bi) do { \
    const unsigned short* bA = &sA[(bi) * (TM * TKK)]; \
    const unsigned short* bB = &sB[(bi) * (TN * TKK)]; \
    bf16x8 bfr0[4], bfr1[4]; \
    _Pragma("unroll") \
    for (int j_ = 0; j_ < 4; ++j_){ \
      int rb = (wn * 64 + j_ * 16 + l15) * TKK; \
      bfr0[j_] = *(const bf16x8*)&bB[rb + co0]; \
      bfr1[j_] = *(const bf16x8*)&bB[rb + co1]; \
    } \
    __builtin_amdgcn_s_setprio(1); \
    _Pragma("unroll") \
    for (int i_ = 0; i_ < 4; ++i_){ \
      int ra = (wm * 64 + i_ * 16 + l15) * TKK; \
      bf16x8 af0 = *(const bf16x8*)&bA[ra + co0]; \
      bf16x8 af1 = *(const bf16x8*)&bA[ra + co1]; \
      _Pragma("unroll") \
      for (int j_ = 0; j_ < 4; ++j_){ \
        acc[i_][j_] = __builtin_amdgcn_mfma_f32_16x16x32_bf16(af0, bfr0[j_], acc[i_][j_], 0, 0, 0); \
        acc[i_][j_] = __builtin_amdgcn_mfma_f32_16x16x32_bf16(af1, bfr1[j_], acc[i_][j_], 0, 0, 0); \
      } \
    } \
    __builtin_amdgcn_s_setprio(0); \
  } while(0)

  // prologue: tiles 0 and 1 in flight (12 loads); wait for tile 0 (leave 6)
  STAGE(0, 0);
  STAGE(1, TKK);
  asm volatile("s_waitcnt vmcnt(6)\n\ts_barrier" ::: "memory");

  #pragma unroll 1
  for (int kt = 0; kt < 16; ++kt){
    if (kt < 14) STAGE((kt + 2) % 3, (kt + 2) * TKK);   // depth-2 prefetch
    COMPUTE(kt % 3);
    if (kt < 14)      asm volatile("s_waitcnt vmcnt(6)\n\ts_barrier" ::: "memory"); // tile kt+1 resident
    else if (kt == 14) asm volatile("s_waitcnt vmcnt(0)\n\ts_barrier" ::: "memory"); // drain tile 15
  }

#undef STAGE
#undef COMPUTE

  #pragma unroll
  for (int i = 0; i < 4; ++i){
    int mbase = m0 + wm * 64 + i * 16 + lh * 4;
    #pragma unroll
    for (int r = 0; r < 4; ++r){
      float bi = bias[mbase + r];
      unsigned short* drow = dst + (size_t)(mbase + r) * S + n0 + wn * 64 + l15;
      #pragma unroll
      for (int j = 0; j < 4; ++j)
        drow[j * 16] = f2bf(acc[i][j][r] + bi);
    }
  }
}

// ---------------------------------------------------------------- packed forward FFT (bf16 in, fp16 out)
__global__ __launch_bounds__(256) void fftfwd2(const unsigned short* __restrict__ src,
                                               const float2* __restrict__ twg,
                                               __half2* __restrict__ hs){
  __shared__ float zr[2112], zi[2112];     // padded exchange: idx x+(x>>5)
  __shared__ float twr[1056], twi[1056];   // W^m, m<1024, padded
  const int t = threadIdx.x;
  #pragma unroll
  for (int q = 0; q < 4; ++q){
    int m = t + 256 * q;
    float2 wv = twg[m];                    // forward: e^{-i th}
    int p = m + (m >> 5);
    twr[p] = wv.x; twi[p] = wv.y;
  }
  const unsigned short* col0 = src + (size_t)(2 * blockIdx.x) * S;
  const unsigned short* col1 = col0 + S;
  float2 v[8], o[8];
  #pragma unroll
  for (int j = 0; j < 8; ++j)
    v[j] = make_float2(bf2f(col0[t + 256 * j]), bf2f(col1[t + 256 * j]));
  dft8_fwd(v, o);
  #pragma unroll
  for (int j = 0; j < 8; ++j){ int x = 8 * t + j; zr[x + (x>>5)] = o[j].x; zi[x + (x>>5)] = o[j].y; }
  __syncthreads();
  {
    int k = t & 7;
    #pragma unroll
    for (int l = 0; l < 8; ++l){ int x = t + 256 * l; v[l] = make_float2(zr[x + (x>>5)], zi[x + (x>>5)]); }
    #pragma unroll
    for (int l = 1; l < 8; ++l) v[l] = cmul(v[l], twf(twr, twi, 32 * l * k));
    dft8_fwd(v, o);
    __syncthreads();
    int base = 8 * t - 7 * k;
    #pragma unroll
    for (int j = 0; j < 8; ++j){ int x = base + 8 * j; zr[x + (x>>5)] = o[j].x; zi[x + (x>>5)] = o[j].y; }
  }
  __syncthreads();
  {
    int k = t & 63;
    #pragma unroll
    for (int l = 0; l < 8; ++l){ int x = t + 256 * l; v[l] = make_float2(zr[x + (x>>5)], zi[x + (x>>5)]); }
    #pragma unroll
    for (int l = 1; l < 8; ++l) v[l] = cmul(v[l], twf(twr, twi, 4 * l * k));
    dft8_fwd(v, o);
    __syncthreads();
    int base = 8 * t - 7 * k;
    #pragma unroll
    for (int j = 0; j < 8; ++j){ int x = base + 64 * j; zr[x + (x>>5)] = o[j].x; zi[x + (x>>5)] = o[j].y; }
  }
  __syncthreads();
  {
    float2 a[4], oa[4], bb[4], ob[4];
    #pragma unroll
    for (int l = 0; l < 4; ++l){
      int xa = t + 512 * l;        a[l]  = make_float2(zr[xa + (xa>>5)], zi[xa + (xa>>5)]);
      int xb = t + 256 + 512 * l;  bb[l] = make_float2(zr[xb + (xb>>5)], zi[xb + (xb>>5)]);
    }
    #pragma unroll
    for (int l = 1; l < 4; ++l){
      a[l]  = cmul(a[l],  twf(twr, twi, l * t));
      bb[l] = cmul(bb[l], twf(twr, twi, l * (t + 256)));
    }
    dft4_fwd(a, oa); dft4_fwd(bb, ob);
    __syncthreads();
    #pragma unroll
    for (int j = 0; j < 4; ++j){
      int xa = t + 512 * j;        zr[xa + (xa>>5)] = oa[j].x; zi[xa + (xa>>5)] = oa[j].y;
      int xb = t + 256 + 512 * j;  zr[xb + (xb>>5)] = ob[j].x; zi[xb + (xb>>5)] = ob[j].y;
    }
  }
  __syncthreads();
  __half2* h0 = hs + (size_t)(2 * blockIdx.x) * HS;
  __half2* h1 = h0 + HS;
  #pragma unroll
  for (int q = 0; q < 4; ++q){
    int k = t + 256 * q;
    int km = (2048 - k) & 2047;
    float2 Zk = make_float2(zr[k + (k>>5)],  zi[k + (k>>5)]);
    float2 Zm = make_float2(zr[km + (km>>5)], zi[km + (km>>5)]);
    h0[k] = __float22half2_rn(make_float2(0.5f * (Zk.x + Zm.x), 0.5f * (Zk.y - Zm.y)));
    h1[k] = __float22half2_rn(make_float2(0.5f * (Zk.y + Zm.y), 0.5f * (Zm.x - Zk.x)));
  }
  if (t == 0){
    float2 Zk = make_float2(zr[1024 + (1024>>5)], zi[1024 + (1024>>5)]);
    h0[1024] = __float22half2_rn(make_float2(Zk.x, 0.f));
    h1[1024] = __float22half2_rn(make_float2(Zk.y, 0.f));
  }
}

// ---------------------------------------------------------------- fused hamilton + half-size real iFFT
__global__ __launch_bounds__(512) void hamifft3(const __half2* __restrict__ hs,
                                                const float2* __restrict__ gfilt,
                                                const float2* __restrict__ twg,
                                                __half* __restrict__ oreal){
  __shared__ __half2 h2s[4][1025];           // 16.4 KB
  __shared__ float zr[2][1056], zi[2][1056]; // 16.9 KB
  __shared__ float twr[1056], twi[1056];     // 8.4 KB (inverse table e^{+i})
  const int t = threadIdx.x;
  const int b = blockIdx.x >> 8;
  const int j = blockIdx.x & 255;
  #pragma unroll
  for (int q = 0; q < 2; ++q){
    int m = t + 512 * q;                   // 0..1023
    float2 wv = twg[m];                    // inverse: e^{+i th}
    int p = m + (m >> 5);
    twr[p] = wv.x; twi[p] = wv.y;
  }
  const size_t CH = (size_t)256 * HS;
  const size_t cQ = ((size_t)b * D4 + j) * HS;
  const size_t cK = cQ + (size_t)NB * D4 * HS;
  const size_t cV = cK + (size_t)NB * D4 * HS;
  const float inv2048 = 1.0f / 2048.0f;
  for (int pass = 0; pass < 3; ++pass){
    int f;
    if (pass < 2) f = t + 512 * pass;      // 0..1023
    else { if (t != 0) break; f = 1024; }
    float2 q0 = __half22float2(hs[cQ + f]),        q1 = __half22float2(hs[cQ + CH + f]),
           q2 = __half22float2(hs[cQ + 2*CH + f]), q3 = __half22float2(hs[cQ + 3*CH + f]);
    float2 k0 = __half22float2(hs[cK + f]),        k1 = __half22float2(hs[cK + CH + f]),
           k2 = __half22float2(hs[cK + 2*CH + f]), k3 = __half22float2(hs[cK + 3*CH + f]);
    float2 v0 = __half22float2(hs[cV + f]),        v1 = __half22float2(hs[cV + CH + f]),
           v2 = __half22float2(hs[cV + 2*CH + f]), v3 = __half22float2(hs[cV + 3*CH + f]);
    float2 hw = csub(csub(csub(cmul(q0,k0), cmul(q1,k1)), cmul(q2,k2)), cmul(q3,k3));
    float2 hx = csub(cadd(cadd(cmul(q0,k1), cmul(q1,k0)), cmul(q2,k3)), cmul(q3,k2));
    float2 hy = cadd(cadd(csub(cmul(q0,k2), cmul(q1,k3)), cmul(q2,k0)), cmul(q3,k1));
    float2 hz = csub(cadd(cadd(cmul(q0,k3), cmul(q1,k2)), cmul(q3,k0)), cmul(q2,k1));
    float2 ow = csub(csub(csub(cmul(hw,v0), cmul(hx,v1)), cmul(hy,v2)), cmul(hz,v3));
    float2 ox = csub(cadd(cadd(cmul(hw,v1), cmul(hx,v0)), cmul(hy,v3)), cmul(hz,v2));
    float2 oy = cadd(cadd(csub(cmul(hw,v2), cmul(hx,v3)), cmul(hy,v0)), cmul(hz,v1));
    float2 oz = csub(cadd(cadd(cmul(hw,v3), cmul(hx,v2)), cmul(hz,v0)), cmul(hy,v1));
    h2s[0][f] = __float22half2_rn(make_float2(ow.x * inv2048, ow.y * inv2048));
    h2s[1][f] = __float22half2_rn(make_float2(ox.x * inv2048, ox.y * inv2048));
    h2s[2][f] = __float22half2_rn(make_float2(oy.x * inv2048, oy.y * inv2048));
    h2s[3][f] = __float22half2_rn(make_float2(oz.x * inv2048, oz.y * inv2048));
  }
  __syncthreads();

  const int h = t >> 8;                    // half id (0/1)
  const int tt = t & 255;
  float* hzr = zr[h]; float* hzi = zi[h];
  for (int cc = 0; cc < 2; ++cc){
    const int c = 2 * cc + h;
    #pragma unroll
    for (int q = 0; q < 4; ++q){
      int k = tt + 256 * q;
      float2 ya = cmul(__half22float2(h2s[c][k]),        gfilt[k]);
      float2 yb = cmul(__half22float2(h2s[c][1024 - k]), gfilt[1024 - k]);
      float2 ybc = make_float2(yb.x, -yb.y);
      float2 e = cadd(ya, ybc);
      float2 od = csub(ya, ybc);
      float2 wv = twf(twr, twi, k);        // e^{+2pi i k/2048}
      float2 wo = cmul(wv, od);
      zr[h][k + (k>>5)] = e.x - wo.y;
      zi[h][k + (k>>5)] = e.y + wo.x;
    }
    __syncthreads();
    #pragma unroll
    for (int s = 0; s < 5; ++s){
      const int p = 1 << (2 * s);
      float2 a[4], o4[4];
      #pragma unroll
      for (int l = 0; l < 4; ++l){ int x = tt + 256 * l; a[l] = make_float2(hzr[x + (x>>5)], hzi[x + (x>>5)]); }
      int k = tt & (p - 1);
      int mstep = k * (512 / p);
      #pragma unroll
      for (int l = 1; l < 4; ++l) a[l] = cmul(a[l], twf(twr, twi, l * mstep));
      dft4_inv(a, o4);
      __syncthreads();
      int base = 4 * tt - 3 * k;
      #pragma unroll
      for (int j2 = 0; j2 < 4; ++j2){ int x = base + j2 * p; hzr[x + (x>>5)] = o4[j2].x; hzi[x + (x>>5)] = o4[j2].y; }
      __syncthreads();
    }
    __half2* ocol2 = (__half2*)(oreal + ((size_t)b * D4 + (j + 256 * c)) * S);
    #pragma unroll
    for (int q = 0; q < 4; ++q){
      int n = tt + 256 * q;
      ocol2[n] = __float22half2_rn(make_float2(hzr[n + (n>>5)], hzi[n + (n>>5)]));
    }
    __syncthreads();
  }
}

// ---------------------------------------------------------------- transpose (fp16 in, fp32 out)
__global__ __launch_bounds__(256) void transpose_kernel(const __half* __restrict__ src,
                                                        float* __restrict__ out){
  __shared__ float tile[32][33];
  const int b  = blockIdx.z;
  const int s0 = blockIdx.x * 32;
  const int d0 = blockIdx.y * 32;
  const int tx = threadIdx.x, ty = threadIdx.y;   // 32 x 8
  #pragma unroll
  for (int i = 0; i < 32; i += 8)
    tile[ty + i][tx] = __half2float(src[((size_t)(b * D4 + d0 + ty + i)) * S + (s0 + tx)]);
  __syncthreads();
  #pragma unroll
  for (int i = 0; i < 32; i += 8)
    out[((size_t)(b * S + s0 + ty + i)) * D4 + (d0 + tx)] = tile[tx][ty + i];
}

// ---------------------------------------------------------------- launch
extern "C" void kernel_launch(void* const* d_in, const int* in_sizes, int n_in,
                              void* d_out, int out_size, void* d_ws, size_t ws_size,
                              hipStream_t stream){
  const float* query  = (const float*)d_in[0];
  const float* memory = (const float*)d_in[1];
  const float* Wq = (const float*)d_in[2];
  const float* bq = (const float*)d_in[3];
  const float* Wk = (const float*)d_in[4];
  const float* bk = (const float*)d_in[5];
  const float* Wv = (const float*)d_in[6];
  const float* bv = (const float*)d_in[7];
  float* out = (float*)d_out;

  const size_t TEN = (size_t)NB * D4 * S;          // 8M elements per tensor
  unsigned short* Xb = (unsigned short*)d_ws;      // [3][NB][D4][S] bf16 (48 MiB)
  __half* oreal = (__half*)(Xb + 3 * TEN);         // [NB][D4][S] fp16 (16 MiB)
  float* wsScale = (float*)(oreal + TEN);          // 2048 floats
  float2* wsGfilt = (float2*)(wsScale + S);        // 1025 float2 (padded to 2048)
  float2* wsTwg   = wsGfilt + S;                   // 2048 float2 (fwd | inv)
  char* A0 = (char*)(wsTwg + S);
  unsigned short* XqB  = (unsigned short*)A0;      // TEN
  unsigned short* XmB  = XqB + TEN;                // TEN
  unsigned short* Wall = XmB + TEN;                // 3*D4*D4
  __half2* hs = (__half2*)A0;                      // [12288][HS] fp16 (50.4 MiB)

  double dop = 0.45 + 0.1 / (1.0 + exp(-0.7));
  double ser = 0.45 + 0.1 / (1.0 + exp(-0.8));
  double nor = 0.45 + 0.1 / (1.0 + exp(-0.6));
  float cmem = (float)(0.4 * dop + 0.3 * ser + 0.3 * nor);
  float alpha = 0.875f, beta = 0.0f;

  prep_kernel<<<8, 256, 0, stream>>>(wsScale, wsGfilt, wsTwg, alpha, beta);

  convert_all<<<19456, 256, 0, stream>>>(query, memory, Wq, Wk, Wv,
                                         XqB, XmB, Wall, wsScale, cmem);

  dim3 gg(S / TN, D4 / TM, 12);
  mfma_gemm_all<<<gg, 512, 0, stream>>>(Wall, XqB, XmB, bq, bk, bv, Xb);

  fftfwd2<<<3 * NB * D4 / 2, 256, 0, stream>>>(Xb, wsTwg, hs);

  hamifft3<<<NB * 256, 512, 0, stream>>>(hs, wsGfilt, wsTwg + 1024, oreal);

  dim3 tg(S / 32, D4 / 32, NB);
  transpose_kernel<<<tg, dim3(32, 8), 0, stream>>>(oreal, out);
}

// Round 17
// 157.407 us; speedup vs baseline: 1.0759x; 1.0759x over previous
//
#include <hip/hip_runtime.h>
#include <hip/hip_fp16.h>
#include <math.h>

#define S 2048
#define D4 1024
#define NB 4
#define HS 1026          // half-spectrum column stride (1025 used)
#define TWOPI 6.283185307179586f

typedef __attribute__((ext_vector_type(8))) short bf16x8;
typedef __attribute__((ext_vector_type(4))) float f32x4;

__device__ __forceinline__ float2 cmul(float2 a, float2 b){
  return make_float2(a.x*b.x - a.y*b.y, a.x*b.y + a.y*b.x);
}
__device__ __forceinline__ float2 cadd(float2 a, float2 b){ return make_float2(a.x+b.x, a.y+b.y); }
__device__ __forceinline__ float2 csub(float2 a, float2 b){ return make_float2(a.x-b.x, a.y-b.y); }

__device__ __forceinline__ unsigned short f2bf(float f){
  unsigned int u = __builtin_bit_cast(unsigned int, f);
  unsigned int r = (u + 0x7FFFu + ((u >> 16) & 1u)) >> 16;
  return (unsigned short)r;
}
__device__ __forceinline__ float bf2f(unsigned short u){
  unsigned int x = (unsigned int)u << 16;
  return __builtin_bit_cast(float, x);
}

__device__ __forceinline__ void gld16(const unsigned short* g, unsigned short* l){
  __builtin_amdgcn_global_load_lds((const __attribute__((address_space(1))) unsigned int*)g,
                                   (__attribute__((address_space(3))) unsigned int*)l,
                                   16, 0, 0);
}

// padded twiddle fetch: table holds W^m for m=0..1023 at index m+(m>>5); W^{m+1024} = -W^m
__device__ __forceinline__ float2 twf(const float* twr, const float* twi, int m){
  int mm = m & 1023;
  float s = (m & 1024) ? -1.f : 1.f;
  int p = mm + (mm >> 5);
  return make_float2(s * twr[p], s * twi[p]);
}

// forward DFT8 (natural-order out): X[k] = sum a[n] W8^{-nk}
__device__ __forceinline__ void dft8_fwd(const float2 a[8], float2 o[8]){
  const float RH = 0.70710678118654752f;
  float2 b0 = cadd(a[0],a[4]), b1 = cadd(a[1],a[5]), b2 = cadd(a[2],a[6]), b3 = cadd(a[3],a[7]);
  float2 c0 = csub(a[0],a[4]);
  float2 t1 = csub(a[1],a[5]);
  float2 c1 = make_float2(RH*(t1.x + t1.y), RH*(t1.y - t1.x));   // * (1-i)/sqrt2
  float2 t2 = csub(a[2],a[6]);
  float2 c2 = make_float2(t2.y, -t2.x);                          // * -i
  float2 t3 = csub(a[3],a[7]);
  float2 c3 = make_float2(RH*(t3.y - t3.x), RH*(-(t3.x + t3.y)));// * (-1-i)/sqrt2
  float2 e0 = cadd(b0,b2), e1 = cadd(b1,b3);
  float2 f0 = csub(b0,b2);
  float2 f1t = csub(b1,b3); float2 f1 = make_float2(f1t.y, -f1t.x);
  o[0] = cadd(e0,e1); o[4] = csub(e0,e1);
  o[2] = cadd(f0,f1); o[6] = csub(f0,f1);
  float2 g0 = cadd(c0,c2), g1 = cadd(c1,c3);
  float2 h0 = csub(c0,c2);
  float2 h1t = csub(c1,c3); float2 h1 = make_float2(h1t.y, -h1t.x);
  o[1] = cadd(g0,g1); o[5] = csub(g0,g1);
  o[3] = cadd(h0,h1); o[7] = csub(h0,h1);
}

__device__ __forceinline__ void dft4_fwd(const float2 a[4], float2 o[4]){
  float2 b0 = cadd(a[0],a[2]), b1 = cadd(a[1],a[3]);
  float2 c0 = csub(a[0],a[2]);
  float2 c1t = csub(a[1],a[3]); float2 c1 = make_float2(c1t.y, -c1t.x);  // * -i
  o[0]=cadd(b0,b1); o[2]=csub(b0,b1); o[1]=cadd(c0,c1); o[3]=csub(c0,c1);
}
__device__ __forceinline__ void dft4_inv(const float2 a[4], float2 o[4]){
  float2 b0 = cadd(a[0],a[2]), b1 = cadd(a[1],a[3]);
  float2 c0 = csub(a[0],a[2]);
  float2 c1t = csub(a[1],a[3]); float2 c1 = make_float2(-c1t.y, c1t.x); // * +i
  o[0]=cadd(b0,b1); o[2]=csub(b0,b1); o[1]=cadd(c0,c1); o[3]=csub(c0,c1);
}

// ---------------------------------------------------------------- prep
__global__ __launch_bounds__(256) void prep_kernel(float* __restrict__ scale,
                                                   float2* __restrict__ gfilt,
                                                   float2* __restrict__ twg,
                                                   float alpha, float beta){
  int i = blockIdx.x * 256 + threadIdx.x;  // 0..2047
  float lam = (float)i / (float)S;
  float w = sinf(alpha * lam) * cosf(-2.0f * lam + beta * lam * lam);
  scale[i] = 0.95f * (1.0f + 0.1f * w);
  if (i <= 1024){
    int im = (2048 - i) & 2047;
    float th1 = 1.5f * atanf(logf((float)i  + 1e-10f));
    float th2 = 1.5f * atanf(logf((float)im + 1e-10f));
    float s1, c1, s2, c2;
    sincosf(3.0f * th1, &s1, &c1);
    sincosf(3.0f * th2, &s2, &c2);
    gfilt[i] = make_float2((c1 + c2) * 0.5f, (s1 - s2) * 0.5f);
  }
  if (i < 1024){
    float s2, c2; sincosf((float)i * (TWOPI / 2048.f), &s2, &c2);
    twg[i]        = make_float2(c2, -s2);
    twg[1024 + i] = make_float2(c2,  s2);
  }
}

// ---------------------------------------------------------------- fused converts
__global__ __launch_bounds__(256) void convert_all(const float* __restrict__ q,
                                                   const float* __restrict__ mem,
                                                   const float* __restrict__ Wq,
                                                   const float* __restrict__ Wk,
                                                   const float* __restrict__ Wv,
                                                   unsigned short* __restrict__ XqB,
                                                   unsigned short* __restrict__ XmB,
                                                   unsigned short* __restrict__ Wall,
                                                   const float* __restrict__ scale,
                                                   float cmem){
  int bid = blockIdx.x;
  if (bid < 8192){
    size_t i = ((size_t)bid * 256 + threadIdx.x) * 4;
    int s = (int)((i / D4) % S);
    float scl = scale[s];
    float4 v = *(const float4*)&q[i];
    ushort4 o;
    o.x = f2bf(v.x * scl); o.y = f2bf(v.y * scl);
    o.z = f2bf(v.z * scl); o.w = f2bf(v.w * scl);
    *(ushort4*)&XqB[i] = o;
  } else if (bid < 16384){
    size_t i = ((size_t)(bid - 8192) * 256 + threadIdx.x) * 4;
    float4 v = *(const float4*)&mem[i];
    ushort4 o;
    o.x = f2bf(v.x * cmem); o.y = f2bf(v.y * cmem);
    o.z = f2bf(v.z * cmem); o.w = f2bf(v.w * cmem);
    *(ushort4*)&XmB[i] = o;
  } else {
    int r = bid - 16384;                    // 0..3071
    int tensor = r >> 10;
    const float* Wsrc = (tensor == 0) ? Wq : (tensor == 1 ? Wk : Wv);
    size_t i = ((size_t)(r & 1023) * 256 + threadIdx.x) * 4;
    float4 v = *(const float4*)&Wsrc[i];
    ushort4 o;
    o.x = f2bf(v.x); o.y = f2bf(v.y);
    o.z = f2bf(v.z); o.w = f2bf(v.w);
    *(ushort4*)&(Wall + (size_t)tensor * D4 * D4)[i] = o;
  }
}

// ---------------------------------------------------------------- MFMA GEMM (2-phase dbuf, bf16 out)
// R9/R13/R15-proven loop (67.3 us): STAGE(next) before COMPUTE(cur), one
// __syncthreads per tile, 64KB LDS -> 2 blocks/CU. Six schedule/geometry
// variants (R7/R8/R12/R14/R16) all matched or regressed — this is the plateau.
#define TM 128
#define TN 128
#define TKK 64
__global__ __launch_bounds__(256) void mfma_gemm_all(const unsigned short* __restrict__ Wall,
                                                     const unsigned short* __restrict__ XqB,
                                                     const unsigned short* __restrict__ XmB,
                                                     const float* __restrict__ bq,
                                                     const float* __restrict__ bk,
                                                     const float* __restrict__ bv,
                                                     unsigned short* __restrict__ Xb){
  __shared__ unsigned short sA[2][TM * TKK];   // 2 x 16 KB
  __shared__ unsigned short sB[2][TN * TKK];   // 2 x 16 KB
  const int z = blockIdx.z;
  const int tensor = z >> 2, b = z & 3;
  const size_t TEN = (size_t)NB * D4 * S;
  const unsigned short* A = Wall + (size_t)tensor * D4 * D4;
  const unsigned short* B = (tensor == 0 ? XqB : XmB) + (size_t)b * S * D4;
  const float* bias = (tensor == 0) ? bq : (tensor == 1 ? bk : bv);
  unsigned short* dst = Xb + (size_t)tensor * TEN + (size_t)b * D4 * S;
  const int m0 = blockIdx.y * TM;
  const int n0 = blockIdx.x * TN;
  const int t = threadIdx.x;
  const int w = t >> 6, l = t & 63;
  const int sr = l >> 3;
  const int sc = ((l & 7) ^ sr) * 8;
  const int wr = (w >> 1) * 64;
  const int wc = (w & 1) * 64;
  const int l15 = l & 15, lh = l >> 4;
  const int co0 = ((lh     ^ (l15 & 7)) * 8);
  const int co1 = (((4+lh) ^ (l15 & 7)) * 8);

  const unsigned short* gA = A + (size_t)(m0 + w * 32 + sr) * D4 + sc;
  const unsigned short* gB = B + (size_t)(n0 + w * 32 + sr) * D4 + sc;

  f32x4 acc[4][4] = {};

#define STAGE(buf, k0) do { \
    _Pragma("unroll") \
    for (int i_ = 0; i_ < 4; ++i_){ \
      gld16(gA + (k0) + (size_t)(8 * i_) * D4, &sA[buf][w * 2048 + i_ * 512]); \
      gld16(gB + (k0) + (size_t)(8 * i_) * D4, &sB[buf][w * 2048 + i_ * 512]); \
    } \
  } while(0)

#define COMPUTE(buf) do { \
    bf16x8 bfr0[4], bfr1[4]; \
    _Pragma("unroll") \
    for (int j_ = 0; j_ < 4; ++j_){ \
      int rb = (wc + j_ * 16 + l15) * TKK; \
      bfr0[j_] = *(const bf16x8*)&sB[buf][rb + co0]; \
      bfr1[j_] = *(const bf16x8*)&sB[buf][rb + co1]; \
    } \
    _Pragma("unroll") \
    for (int i_ = 0; i_ < 4; ++i_){ \
      int ra = (wr + i_ * 16 + l15) * TKK; \
      bf16x8 af0 = *(const bf16x8*)&sA[buf][ra + co0]; \
      bf16x8 af1 = *(const bf16x8*)&sA[buf][ra + co1]; \
      _Pragma("unroll") \
      for (int j_ = 0; j_ < 4; ++j_){ \
        acc[i_][j_] = __builtin_amdgcn_mfma_f32_16x16x32_bf16(af0, bfr0[j_], acc[i_][j_], 0, 0, 0); \
        acc[i_][j_] = __builtin_amdgcn_mfma_f32_16x16x32_bf16(af1, bfr1[j_], acc[i_][j_], 0, 0, 0); \
      } \
    } \
  } while(0)

  STAGE(0, 0);
  __syncthreads();
  #pragma unroll 1
  for (int k0 = 0; k0 < 16; ++k0){
    if (k0 < 15) STAGE((k0 + 1) & 1, (k0 + 1) * TKK);
    COMPUTE(k0 & 1);
    __syncthreads();
  }

#undef STAGE
#undef COMPUTE

  #pragma unroll
  for (int i = 0; i < 4; ++i){
    int mbase = m0 + wr + i * 16 + lh * 4;
    #pragma unroll
    for (int r = 0; r < 4; ++r){
      float bi = bias[mbase + r];
      unsigned short* drow = dst + (size_t)(mbase + r) * S + n0 + wc + l15;
      #pragma unroll
      for (int j = 0; j < 4; ++j)
        drow[j * 16] = f2bf(acc[i][j][r] + bi);
    }
  }
}

// ---------------------------------------------------------------- packed forward FFT (bf16 in, fp16 out)
__global__ __launch_bounds__(256) void fftfwd2(const unsigned short* __restrict__ src,
                                               const float2* __restrict__ twg,
                                               __half2* __restrict__ hs){
  __shared__ float zr[2112], zi[2112];     // padded exchange: idx x+(x>>5)
  __shared__ float twr[1056], twi[1056];   // W^m, m<1024, padded
  const int t = threadIdx.x;
  #pragma unroll
  for (int q = 0; q < 4; ++q){
    int m = t + 256 * q;
    float2 wv = twg[m];                    // forward: e^{-i th}
    int p = m + (m >> 5);
    twr[p] = wv.x; twi[p] = wv.y;
  }
  const unsigned short* col0 = src + (size_t)(2 * blockIdx.x) * S;
  const unsigned short* col1 = col0 + S;
  float2 v[8], o[8];
  #pragma unroll
  for (int j = 0; j < 8; ++j)
    v[j] = make_float2(bf2f(col0[t + 256 * j]), bf2f(col1[t + 256 * j]));
  dft8_fwd(v, o);
  #pragma unroll
  for (int j = 0; j < 8; ++j){ int x = 8 * t + j; zr[x + (x>>5)] = o[j].x; zi[x + (x>>5)] = o[j].y; }
  __syncthreads();
  {
    int k = t & 7;
    #pragma unroll
    for (int l = 0; l < 8; ++l){ int x = t + 256 * l; v[l] = make_float2(zr[x + (x>>5)], zi[x + (x>>5)]); }
    #pragma unroll
    for (int l = 1; l < 8; ++l) v[l] = cmul(v[l], twf(twr, twi, 32 * l * k));
    dft8_fwd(v, o);
    __syncthreads();
    int base = 8 * t - 7 * k;
    #pragma unroll
    for (int j = 0; j < 8; ++j){ int x = base + 8 * j; zr[x + (x>>5)] = o[j].x; zi[x + (x>>5)] = o[j].y; }
  }
  __syncthreads();
  {
    int k = t & 63;
    #pragma unroll
    for (int l = 0; l < 8; ++l){ int x = t + 256 * l; v[l] = make_float2(zr[x + (x>>5)], zi[x + (x>>5)]); }
    #pragma unroll
    for (int l = 1; l < 8; ++l) v[l] = cmul(v[l], twf(twr, twi, 4 * l * k));
    dft8_fwd(v, o);
    __syncthreads();
    int base = 8 * t - 7 * k;
    #pragma unroll
    for (int j = 0; j < 8; ++j){ int x = base + 64 * j; zr[x + (x>>5)] = o[j].x; zi[x + (x>>5)] = o[j].y; }
  }
  __syncthreads();
  {
    float2 a[4], oa[4], bb[4], ob[4];
    #pragma unroll
    for (int l = 0; l < 4; ++l){
      int xa = t + 512 * l;        a[l]  = make_float2(zr[xa + (xa>>5)], zi[xa + (xa>>5)]);
      int xb = t + 256 + 512 * l;  bb[l] = make_float2(zr[xb + (xb>>5)], zi[xb + (xb>>5)]);
    }
    #pragma unroll
    for (int l = 1; l < 4; ++l){
      a[l]  = cmul(a[l],  twf(twr, twi, l * t));
      bb[l] = cmul(bb[l], twf(twr, twi, l * (t + 256)));
    }
    dft4_fwd(a, oa); dft4_fwd(bb, ob);
    __syncthreads();
    #pragma unroll
    for (int j = 0; j < 4; ++j){
      int xa = t + 512 * j;        zr[xa + (xa>>5)] = oa[j].x; zi[xa + (xa>>5)] = oa[j].y;
      int xb = t + 256 + 512 * j;  zr[xb + (xb>>5)] = ob[j].x; zi[xb + (xb>>5)] = ob[j].y;
    }
  }
  __syncthreads();
  __half2* h0 = hs + (size_t)(2 * blockIdx.x) * HS;
  __half2* h1 = h0 + HS;
  #pragma unroll
  for (int q = 0; q < 4; ++q){
    int k = t + 256 * q;
    int km = (2048 - k) & 2047;
    float2 Zk = make_float2(zr[k + (k>>5)],  zi[k + (k>>5)]);
    float2 Zm = make_float2(zr[km + (km>>5)], zi[km + (km>>5)]);
    h0[k] = __float22half2_rn(make_float2(0.5f * (Zk.x + Zm.x), 0.5f * (Zk.y - Zm.y)));
    h1[k] = __float22half2_rn(make_float2(0.5f * (Zk.y + Zm.y), 0.5f * (Zm.x - Zk.x)));
  }
  if (t == 0){
    float2 Zk = make_float2(zr[1024 + (1024>>5)], zi[1024 + (1024>>5)]);
    h0[1024] = __float22half2_rn(make_float2(Zk.x, 0.f));
    h1[1024] = __float22half2_rn(make_float2(Zk.y, 0.f));
  }
}

// ---------------------------------------------------------------- fused hamilton + half-size real iFFT
__global__ __launch_bounds__(512) void hamifft3(const __half2* __restrict__ hs,
                                                const float2* __restrict__ gfilt,
                                                const float2* __restrict__ twg,
                                                __half* __restrict__ oreal){
  __shared__ __half2 h2s[4][1025];           // 16.4 KB
  __shared__ float zr[2][1056], zi[2][1056]; // 16.9 KB
  __shared__ float twr[1056], twi[1056];     // 8.4 KB (inverse table e^{+i})
  const int t = threadIdx.x;
  const int b = blockIdx.x >> 8;
  const int j = blockIdx.x & 255;
  #pragma unroll
  for (int q = 0; q < 2; ++q){
    int m = t + 512 * q;                   // 0..1023
    float2 wv = twg[m];                    // inverse: e^{+i th}
    int p = m + (m >> 5);
    twr[p] = wv.x; twi[p] = wv.y;
  }
  const size_t CH = (size_t)256 * HS;
  const size_t cQ = ((size_t)b * D4 + j) * HS;
  const size_t cK = cQ + (size_t)NB * D4 * HS;
  const size_t cV = cK + (size_t)NB * D4 * HS;
  const float inv2048 = 1.0f / 2048.0f;
  for (int pass = 0; pass < 3; ++pass){
    int f;
    if (pass < 2) f = t + 512 * pass;      // 0..1023
    else { if (t != 0) break; f = 1024; }
    float2 q0 = __half22float2(hs[cQ + f]),        q1 = __half22float2(hs[cQ + CH + f]),
           q2 = __half22float2(hs[cQ + 2*CH + f]), q3 = __half22float2(hs[cQ + 3*CH + f]);
    float2 k0 = __half22float2(hs[cK + f]),        k1 = __half22float2(hs[cK + CH + f]),
           k2 = __half22float2(hs[cK + 2*CH + f]), k3 = __half22float2(hs[cK + 3*CH + f]);
    float2 v0 = __half22float2(hs[cV + f]),        v1 = __half22float2(hs[cV + CH + f]),
           v2 = __half22float2(hs[cV + 2*CH + f]), v3 = __half22float2(hs[cV + 3*CH + f]);
    float2 hw = csub(csub(csub(cmul(q0,k0), cmul(q1,k1)), cmul(q2,k2)), cmul(q3,k3));
    float2 hx = csub(cadd(cadd(cmul(q0,k1), cmul(q1,k0)), cmul(q2,k3)), cmul(q3,k2));
    float2 hy = cadd(cadd(csub(cmul(q0,k2), cmul(q1,k3)), cmul(q2,k0)), cmul(q3,k1));
    float2 hz = csub(cadd(cadd(cmul(q0,k3), cmul(q1,k2)), cmul(q3,k0)), cmul(q2,k1));
    float2 ow = csub(csub(csub(cmul(hw,v0), cmul(hx,v1)), cmul(hy,v2)), cmul(hz,v3));
    float2 ox = csub(cadd(cadd(cmul(hw,v1), cmul(hx,v0)), cmul(hy,v3)), cmul(hz,v2));
    float2 oy = cadd(cadd(csub(cmul(hw,v2), cmul(hx,v3)), cmul(hy,v0)), cmul(hz,v1));
    float2 oz = csub(cadd(cadd(cmul(hw,v3), cmul(hx,v2)), cmul(hz,v0)), cmul(hy,v1));
    h2s[0][f] = __float22half2_rn(make_float2(ow.x * inv2048, ow.y * inv2048));
    h2s[1][f] = __float22half2_rn(make_float2(ox.x * inv2048, ox.y * inv2048));
    h2s[2][f] = __float22half2_rn(make_float2(oy.x * inv2048, oy.y * inv2048));
    h2s[3][f] = __float22half2_rn(make_float2(oz.x * inv2048, oz.y * inv2048));
  }
  __syncthreads();

  const int h = t >> 8;                    // half id (0/1)
  const int tt = t & 255;
  float* hzr = zr[h]; float* hzi = zi[h];
  for (int cc = 0; cc < 2; ++cc){
    const int c = 2 * cc + h;
    #pragma unroll
    for (int q = 0; q < 4; ++q){
      int k = tt + 256 * q;
      float2 ya = cmul(__half22float2(h2s[c][k]),        gfilt[k]);
      float2 yb = cmul(__half22float2(h2s[c][1024 - k]), gfilt[1024 - k]);
      float2 ybc = make_float2(yb.x, -yb.y);
      float2 e = cadd(ya, ybc);
      float2 od = csub(ya, ybc);
      float2 wv = twf(twr, twi, k);        // e^{+2pi i k/2048}
      float2 wo = cmul(wv, od);
      zr[h][k + (k>>5)] = e.x - wo.y;
      zi[h][k + (k>>5)] = e.y + wo.x;
    }
    __syncthreads();
    #pragma unroll
    for (int s = 0; s < 5; ++s){
      const int p = 1 << (2 * s);
      float2 a[4], o4[4];
      #pragma unroll
      for (int l = 0; l < 4; ++l){ int x = tt + 256 * l; a[l] = make_float2(hzr[x + (x>>5)], hzi[x + (x>>5)]); }
      int k = tt & (p - 1);
      int mstep = k * (512 / p);
      #pragma unroll
      for (int l = 1; l < 4; ++l) a[l] = cmul(a[l], twf(twr, twi, l * mstep));
      dft4_inv(a, o4);
      __syncthreads();
      int base = 4 * tt - 3 * k;
      #pragma unroll
      for (int j2 = 0; j2 < 4; ++j2){ int x = base + j2 * p; hzr[x + (x>>5)] = o4[j2].x; hzi[x + (x>>5)] = o4[j2].y; }
      __syncthreads();
    }
    __half2* ocol2 = (__half2*)(oreal + ((size_t)b * D4 + (j + 256 * c)) * S);
    #pragma unroll
    for (int q = 0; q < 4; ++q){
      int n = tt + 256 * q;
      ocol2[n] = __float22half2_rn(make_float2(hzr[n + (n>>5)], hzi[n + (n>>5)]));
    }
    __syncthreads();
  }
}

// ---------------------------------------------------------------- transpose (fp16 in, fp32 out)
__global__ __launch_bounds__(256) void transpose_kernel(const __half* __restrict__ src,
                                                        float* __restrict__ out){
  __shared__ float tile[32][33];
  const int b  = blockIdx.z;
  const int s0 = blockIdx.x * 32;
  const int d0 = blockIdx.y * 32;
  const int tx = threadIdx.x, ty = threadIdx.y;   // 32 x 8
  #pragma unroll
  for (int i = 0; i < 32; i += 8)
    tile[ty + i][tx] = __half2float(src[((size_t)(b * D4 + d0 + ty + i)) * S + (s0 + tx)]);
  __syncthreads();
  #pragma unroll
  for (int i = 0; i < 32; i += 8)
    out[((size_t)(b * S + s0 + ty + i)) * D4 + (d0 + tx)] = tile[tx][ty + i];
}

// ---------------------------------------------------------------- launch
extern "C" void kernel_launch(void* const* d_in, const int* in_sizes, int n_in,
                              void* d_out, int out_size, void* d_ws, size_t ws_size,
                              hipStream_t stream){
  const float* query  = (const float*)d_in[0];
  const float* memory = (const float*)d_in[1];
  const float* Wq = (const float*)d_in[2];
  const float* bq = (const float*)d_in[3];
  const float* Wk = (const float*)d_in[4];
  const float* bk = (const float*)d_in[5];
  const float* Wv = (const float*)d_in[6];
  const float* bv = (const float*)d_in[7];
  float* out = (float*)d_out;

  const size_t TEN = (size_t)NB * D4 * S;          // 8M elements per tensor
  unsigned short* Xb = (unsigned short*)d_ws;      // [3][NB][D4][S] bf16 (48 MiB)
  __half* oreal = (__half*)(Xb + 3 * TEN);         // [NB][D4][S] fp16 (16 MiB)
  float* wsScale = (float*)(oreal + TEN);          // 2048 floats
  float2* wsGfilt = (float2*)(wsScale + S);        // 1025 float2 (padded to 2048)
  float2* wsTwg   = wsGfilt + S;                   // 2048 float2 (fwd | inv)
  char* A0 = (char*)(wsTwg + S);
  unsigned short* XqB  = (unsigned short*)A0;      // TEN
  unsigned short* XmB  = XqB + TEN;                // TEN
  unsigned short* Wall = XmB + TEN;                // 3*D4*D4
  __half2* hs = (__half2*)A0;                      // [12288][HS] fp16 (50.4 MiB)

  double dop = 0.45 + 0.1 / (1.0 + exp(-0.7));
  double ser = 0.45 + 0.1 / (1.0 + exp(-0.8));
  double nor = 0.45 + 0.1 / (1.0 + exp(-0.6));
  float cmem = (float)(0.4 * dop + 0.3 * ser + 0.3 * nor);
  float alpha = 0.875f, beta = 0.0f;

  prep_kernel<<<8, 256, 0, stream>>>(wsScale, wsGfilt, wsTwg, alpha, beta);

  convert_all<<<19456, 256, 0, stream>>>(query, memory, Wq, Wk, Wv,
                                         XqB, XmB, Wall, wsScale, cmem);

  dim3 gg(S / TN, D4 / TM, 12);
  mfma_gemm_all<<<gg, 256, 0, stream>>>(Wall, XqB, XmB, bq, bk, bv, Xb);

  fftfwd2<<<3 * NB * D4 / 2, 256, 0, stream>>>(Xb, wsTwg, hs);

  hamifft3<<<NB * 256, 512, 0, stream>>>(hs, wsGfilt, wsTwg + 1024, oreal);

  dim3 tg(S / 32, D4 / 32, NB);
  transpose_kernel<<<tg, dim3(32, 8), 0, stream>>>(oreal, out);
}